// Round 3
// baseline (506.749 us; speedup 1.0000x reference)
//
#include <hip/hip_runtime.h>
#include <math.h>

#define B_           1024
#define S_           200
#define H_           128
#define VOCAB_       100000
#define PAD_ID_      99998
#define INTEREST_ID_ 99999
#define NTHREADS_    512   // 8 waves/block; 1024 blocks -> 4 blocks/CU

// One block per batch row. Phase ORDER is the point of this revision:
//   A. zero-fill out[b,:] with float4 stores FIRST (fire-and-forget; drains
//      to L2 while we compute)
//   B. score compute: tanh(hs[b,s,:] + hs[b,0,:]) . w  -- wave handles 2 rows
//      per iter (half-wave per row, float4/lane, 5-step xor-shuffle reduce)
//   C. __syncthreads (stores already retired by now -> cheap vmcnt drain)
//   D. masked softmax over 200 scores + atomicAdd scatter into the row this
//      block exclusively owns (atomics resolve at the same L2 the zeros hit).
__global__ __launch_bounds__(NTHREADS_) void rd90220_fused_v3(
    const float* __restrict__ hs,
    const int*   __restrict__ ids,
    const float* __restrict__ w,
    const float* __restrict__ bp,
    float*       __restrict__ out)
{
    __shared__ float s_scores[S_];
    __shared__ float s_red[16];

    const int batch = blockIdx.x;
    const int tid   = threadIdx.x;
    const int wave  = tid >> 6;
    const int lane  = tid & 63;
    const int half  = lane >> 5;   // which of the 2 rows this half-wave handles
    const int hl    = lane & 31;   // lane within half: h = hl*4 .. hl*4+3

    const float* hsb  = hs + (size_t)batch * (S_ * H_);
    float*       rowo = out + (size_t)batch * VOCAB_;

    // ---- Phase A: zero this block's output row (25000 float4 = 400 KB).
    // Stores are issued up front so they overlap the score-phase loads.
    {
        float4* rowo4 = (float4*)rowo;
        const float4 z = make_float4(0.f, 0.f, 0.f, 0.f);
        #pragma unroll 4
        for (int i = tid; i < VOCAB_ / 4; i += NTHREADS_)
            rowo4[i] = z;
    }

    // Load token id early (overlaps with everything below).
    int   id    = 0;
    bool  valid = false;
    if (tid < S_) {
        id    = ids[batch * S_ + tid];
        valid = (id != PAD_ID_) && (id != INTEREST_ID_);
    }

    // ---- Phase B: scores. Per-lane constants then 2 rows per wave-iter.
    const float4 key = ((const float4*)hsb)[hl];
    const float4 wv  = ((const float4*)w)[hl];

    for (int s0 = wave * 2; s0 < S_; s0 += 16) {
        const int s = s0 + half;                      // covers every s in [0,200)
        const float4 x = ((const float4*)(hsb + s * H_))[hl];
        float acc = tanhf(x.x + key.x) * wv.x
                  + tanhf(x.y + key.y) * wv.y
                  + tanhf(x.z + key.z) * wv.z
                  + tanhf(x.w + key.w) * wv.w;
        #pragma unroll
        for (int off = 16; off; off >>= 1)            // xor masks <32 stay in-half
            acc += __shfl_xor(acc, off, 64);
        if (hl == 0) s_scores[s] = acc;
    }

    __syncthreads();   // scores visible; zero stores fully drained to L2

    // ---- Phase D: masked softmax over 200 scores ----
    const float bias = bp[0];
    float sc = (tid < S_ && valid) ? (s_scores[tid] + bias) : -INFINITY;

    float m = sc;
    #pragma unroll
    for (int off = 32; off; off >>= 1)
        m = fmaxf(m, __shfl_down(m, off, 64));
    if (lane == 0) s_red[wave] = m;
    __syncthreads();
    m = fmaxf(fmaxf(fmaxf(s_red[0], s_red[1]), fmaxf(s_red[2], s_red[3])),
              fmaxf(fmaxf(s_red[4], s_red[5]), fmaxf(s_red[6], s_red[7])));

    const float e = (tid < S_ && valid) ? expf(sc - m) : 0.0f;
    float t = e;
    #pragma unroll
    for (int off = 32; off; off >>= 1)
        t += __shfl_down(t, off, 64);
    if (lane == 0) s_red[8 + wave] = t;
    __syncthreads();
    const float sum = (s_red[8]  + s_red[9])  + (s_red[10] + s_red[11])
                    + (s_red[12] + s_red[13]) + (s_red[14] + s_red[15]);

    // ---- Scatter (duplicate ids within a row possible -> atomicAdd) ----
    if (tid < S_ && valid) {
        atomicAdd(&rowo[id], e / sum);
    }
}

extern "C" void kernel_launch(void* const* d_in, const int* in_sizes, int n_in,
                              void* d_out, int out_size, void* d_ws, size_t ws_size,
                              hipStream_t stream) {
    const float* hs  = (const float*)d_in[0];
    const int*   ids = (const int*)d_in[1];
    const float* w   = (const float*)d_in[2];
    const float* bp  = (const float*)d_in[3];
    float*       out = (float*)d_out;

    rd90220_fused_v3<<<B_, NTHREADS_, 0, stream>>>(hs, ids, w, bp, out);
}